// Round 16
// baseline (150.350 us; speedup 1.0000x reference)
//
#include <hip/hip_runtime.h>

#define N_NODES 30000
#define N_EDGES 480000
#define D 128
#define H 3
#define BN_EPS 1e-5f
#define M_TOT (H * N_NODES)
#define E_TOT (H * N_EDGES)

#define NCH 64                       // chunks per hop
#define CHE (N_EDGES / NCH)          // 7500 edges per chunk
#define NBKT 512                     // dst buckets per hop (dst>>6)
#define NBKT_TOT (H * NBKT)          // 1536
#define CELLS (NBKT_TOT * NCH)       // 98304 = 96 * 1024
#define SCAN_NBLK (CELLS / 1024)     // 96
#define CONV_N4 (3 * N_NODES * D / 4)        // slices 1..3 (unswizzled, for agg)
#define CONV_BLK ((CONV_N4 + 255) / 256)     // 11250
#define TILES ((N_NODES + 63) / 64)          // 469
#define S0_BLK (N_NODES * 16 / 256)          // 1875: slice-0 swizzled conv
#define PREP_FIX (H * NCH + 9)               // 201
#define AGG_HALF (M_TOT / 4)                 // 22500 blocks per column pass

typedef __attribute__((ext_vector_type(8))) short short8v;   // 8 x bf16
typedef __attribute__((ext_vector_type(4))) float f32x4;     // MFMA accumulator

__device__ __forceinline__ ushort f2bf(float f) {            // RNE f32 -> bf16
    uint u = __float_as_uint(f);
    u += 0x7fffu + ((u >> 16) & 1u);
    return (ushort)(u >> 16);
}
__device__ __forceinline__ float bf2f(ushort b) {
    return __uint_as_float(((uint)b) << 16);
}

// acc += bf16_pair(w) . bf16_pair(msk)   (one VOP3P instruction)
#define DOT2(accv, w, msk) \
    asm("v_dot2_f32_bf16 %0, %1, %2, %0" : "+v"(accv) : "v"(w), "v"(msk))

// async global -> LDS, 16B per lane (dest = uniform base + lane*16)
__device__ __forceinline__ void gload16(const void* g, void* l) {
    __builtin_amdgcn_global_load_lds(
        (const __attribute__((address_space(1))) void*)g,
        (__attribute__((address_space(3))) void*)l, 16, 0, 0);
}

// ---------------- merged prep ----------------
// blocks: [0,192) bincount | [192,200) Wt^T swizzled | 200 scof |
// [201,201+1875) xs slice0 -> bf16 swizzled | rest: slices 1..3 unswizzled
__global__ __launch_bounds__(256) void prep_k(
    const float* __restrict__ xs, const int* __restrict__ ei,
    const float* __restrict__ lW1, const float* __restrict__ lW2,
    const float* __restrict__ cW1, const float* __restrict__ cW2,
    const float* __restrict__ lb1, const float* __restrict__ lg,
    const float* __restrict__ lbt, const float* __restrict__ lm,
    const float* __restrict__ lv,
    const float* __restrict__ cb1, const float* __restrict__ cg,
    const float* __restrict__ cbt, const float* __restrict__ cm,
    const float* __restrict__ cv,
    const float* __restrict__ lb2, const float* __restrict__ cb2,
    ushort* __restrict__ Wt, float* __restrict__ scof,
    ushort* __restrict__ xball, int* __restrict__ cnts)
{
    const int bid = blockIdx.x;
    const int tid = threadIdx.x;
    if (bid < H * NCH) {                     // CSR pass 1: per-chunk histogram
        __shared__ int hc[NBKT];
        const int hop = bid >> 6, c = bid & 63;
        for (int i = tid; i < NBKT; i += 256) hc[i] = 0;
        __syncthreads();
        const int* dstp = ei + (size_t)hop * 2 * N_EDGES + N_EDGES + c * CHE;
        for (int i = tid; i < CHE; i += 256)
            atomicAdd(&hc[dstp[i] >> 6], 1);
        __syncthreads();
        for (int b = tid; b < NBKT; b += 256)
            cnts[((hop * NBKT + b) << 6) | c] = hc[b];
    } else if (bid < H * NCH + 8) {          // Wt[n][k^swz] = W[k][n] (bf16)
        const int mat = bid - H * NCH;
        const float* src;
        if (mat == 0) src = lW1;
        else if (mat == 1) src = lW2;
        else {
            const int k = (mat - 2) >> 1;
            src = ((mat & 1) == 0 ? cW1 : cW2) + (size_t)k * D * D;
        }
        ushort* dst = Wt + (size_t)mat * D * D;
        for (int idx = tid; idx < D * D; idx += 256) {
            const int n = idx >> 7, k = idx & 127;
            dst[n * 128 + (k ^ ((n & 7) << 3))] = f2bf(src[k * D + n]);
        }
    } else if (bid == H * NCH + 8) {         // BN scale/offset + total bias
        for (int t = tid; t < 512; t += 256) {
            const int L = t >> 7, c = t & 127;
            float g, v, b, m, bt;
            if (L == 0) { g = lg[c]; v = lv[c]; b = lb1[c]; m = lm[c]; bt = lbt[c]; }
            else {
                const int k = L - 1;
                g = cg[k * D + c]; v = cv[k * D + c]; b = cb1[k * D + c];
                m = cm[k * D + c]; bt = cbt[k * D + c];
            }
            const float s = g * rsqrtf(v + BN_EPS);
            scof[L * 256 + c] = s;
            scof[L * 256 + 128 + c] = (b - m) * s + bt;
        }
        if (tid < 128) {                     // btot = lb2 + sum_k cb2[k]
            float t = lb2[tid];
            for (int k = 0; k < H; ++k) t += cb2[k * D + tid];
            scof[1024 + tid] = t;
        }
    } else if (bid < PREP_FIX + S0_BLK) {    // slice 0: f32 -> bf16, swizzled
        const int i = (bid - PREP_FIX) * 256 + tid;   // 16B chunk id
        const int row = i >> 4, c = i & 15;
        const float* sp = xs + (size_t)row * D + c * 8;
        const float4 f0 = ((const float4*)sp)[0];
        const float4 f1 = ((const float4*)sp)[1];
        uint4 o;
        o.x = (uint)f2bf(f0.x) | ((uint)f2bf(f0.y) << 16);
        o.y = (uint)f2bf(f0.z) | ((uint)f2bf(f0.w) << 16);
        o.z = (uint)f2bf(f1.x) | ((uint)f2bf(f1.y) << 16);
        o.w = (uint)f2bf(f1.z) | ((uint)f2bf(f1.w) << 16);
        ((uint4*)xball)[(size_t)row * 16 + (c ^ (row & 7))] = o;
    } else {                                 // slices 1..3 unswizzled (agg)
        const int i = (bid - PREP_FIX - S0_BLK) * 256 + tid;
        if (i < CONV_N4) {
            const float4 v = ((const float4*)(xs + (size_t)N_NODES * D))[i];
            ushort4 o;
            o.x = f2bf(v.x); o.y = f2bf(v.y); o.z = f2bf(v.z); o.w = f2bf(v.w);
            ((ushort4*)(xball + (size_t)N_NODES * D))[i] = o;
        }
    }
}

// ---------------- Layer-parallel MLP: async stage, ONE barrier -------------
__global__ __launch_bounds__(256) void layerpar_k(
    const ushort* __restrict__ xball, const ushort* __restrict__ zb,
    const ushort* __restrict__ Wt, const float* __restrict__ scof,
    ushort* __restrict__ parts)
{
    __shared__ ushort Xs[64 * 128];      // 16 KB
    __shared__ ushort Ws1[128 * 128];    // 32 KB
    __shared__ ushort Ws2[128 * 128];    // 32 KB
    const int L = blockIdx.x & 3, tile = blockIdx.x >> 2;
    const int row0 = tile * 64;
    const int tid = threadIdx.x;
    const int wave = tid >> 6, lane = tid & 63;
    const int m16 = lane & 15, kq = lane >> 4;

    const ushort* W1t = Wt + (size_t)(2 * L) * D * D;
    const ushort* W2t = W1t + D * D;
    const ushort* Xsrc = (L == 0) ? xball : zb + (size_t)(L - 1) * N_NODES * D;
    const float* scL = scof + L * 256;

#pragma unroll
    for (int it = 0; it < 4; ++it) {
        const int r = wave * 16 + it * 4;
        gload16(Xsrc + (size_t)(row0 + r) * 128 + lane * 8, &Xs[r * 128]);
    }
#pragma unroll
    for (int it = 0; it < 8; ++it) {
        const int r = wave * 32 + it * 4;
        gload16(W1t + (size_t)r * 128 + lane * 8, &Ws1[r * 128]);
        gload16(W2t + (size_t)r * 128 + lane * 8, &Ws2[r * 128]);
    }
    __syncthreads();   // waits vmcnt(0): all three tiles resident

    const int sx = (m16 & 7) << 3;

    short8v a[4];
#pragma unroll
    for (int kk = 0; kk < 4; ++kk)
        a[kk] = *(const short8v*)(&Xs[(wave * 16 + m16) * 128 + ((kk * 32 + kq * 8) ^ sx)]);

    f32x4 acc[8];
#pragma unroll
    for (int t = 0; t < 8; ++t) acc[t] = (f32x4){0.f, 0.f, 0.f, 0.f};
#pragma unroll
    for (int kk = 0; kk < 4; ++kk) {
#pragma unroll
        for (int t = 0; t < 8; ++t) {
            const short8v b = *(const short8v*)(&Ws1[(t * 16 + m16) * 128 + ((kk * 32 + kq * 8) ^ sx)]);
            acc[t] = __builtin_amdgcn_mfma_f32_16x16x32_bf16(a[kk], b, acc[t], 0, 0, 0);
        }
    }

#pragma unroll
    for (int t = 0; t < 8; ++t) {
        const int n = t * 16 + m16;
        const float sc = scL[n], of = scL[128 + n];
#pragma unroll
        for (int r = 0; r < 4; ++r) {
            const int ml = wave * 16 + kq * 4 + r;
            Xs[ml * 128 + (n ^ (((kq * 4 + r) & 7) << 3))] =
                f2bf(fmaxf(acc[t][r] * sc + of, 0.f));
        }
    }

    short8v ah[4];
#pragma unroll
    for (int kk = 0; kk < 4; ++kk)
        ah[kk] = *(const short8v*)(&Xs[(wave * 16 + m16) * 128 + ((kk * 32 + kq * 8) ^ sx)]);
    f32x4 accO[8];
#pragma unroll
    for (int t = 0; t < 8; ++t) accO[t] = (f32x4){0.f, 0.f, 0.f, 0.f};
#pragma unroll
    for (int kk = 0; kk < 4; ++kk) {
#pragma unroll
        for (int t = 0; t < 8; ++t) {
            const short8v b = *(const short8v*)(&Ws2[(t * 16 + m16) * 128 + ((kk * 32 + kq * 8) ^ sx)]);
            accO[t] = __builtin_amdgcn_mfma_f32_16x16x32_bf16(ah[kk], b, accO[t], 0, 0, 0);
        }
    }

    ushort* pL = parts + (size_t)L * N_NODES * D;
#pragma unroll
    for (int t = 0; t < 8; ++t) {
        const int n = t * 16 + m16;
#pragma unroll
        for (int r = 0; r < 4; ++r) {
            const int gr = row0 + wave * 16 + kq * 4 + r;
            if (gr < N_NODES) pL[(size_t)gr * D + n] = f2bf(accO[t][r]);
        }
    }
}

// ---------------- reduce: out = sum_L parts[L] + btot (f32, fixed order) ---
__global__ __launch_bounds__(256) void reduce_k(const ushort* __restrict__ parts,
                                                const float* __restrict__ scof,
                                                float* __restrict__ out)
{
    const int i = blockIdx.x * 256 + threadIdx.x;    // uint2 granule = 4 cols
    const size_t LS = (size_t)N_NODES * D / 4;       // uint2 per layer
    const uint2* pp = (const uint2*)parts;
    const uint2 q0 = pp[i];
    const uint2 q1 = pp[i + LS];
    const uint2 q2 = pp[i + 2 * LS];
    const uint2 q3 = pp[i + 3 * LS];
    const float4 bb = ((const float4*)(scof + 1024))[i & 31];
    float4 s;
    s.x = ((bf2f((ushort)(q0.x & 0xffff)) + bf2f((ushort)(q1.x & 0xffff))) +
           (bf2f((ushort)(q2.x & 0xffff)) + bf2f((ushort)(q3.x & 0xffff)))) + bb.x;
    s.y = ((bf2f((ushort)(q0.x >> 16)) + bf2f((ushort)(q1.x >> 16))) +
           (bf2f((ushort)(q2.x >> 16)) + bf2f((ushort)(q3.x >> 16)))) + bb.y;
    s.z = ((bf2f((ushort)(q0.y & 0xffff)) + bf2f((ushort)(q1.y & 0xffff))) +
           (bf2f((ushort)(q2.y & 0xffff)) + bf2f((ushort)(q3.y & 0xffff)))) + bb.z;
    s.w = ((bf2f((ushort)(q0.y >> 16)) + bf2f((ushort)(q1.y >> 16))) +
           (bf2f((ushort)(q2.y >> 16)) + bf2f((ushort)(q3.y >> 16)))) + bb.w;
    ((float4*)out)[i] = s;
}

// ---------------- CSR scans ----------------
__global__ __launch_bounds__(1024) void scanA_k(int* __restrict__ cnts,
                                                int* __restrict__ bsums) {
    __shared__ int sh[1024];
    const int tid = threadIdx.x;
    const int i = blockIdx.x * 1024 + tid;
    const int v = cnts[i];
    sh[tid] = v;
    __syncthreads();
    int val = v;
    for (int off = 1; off < 1024; off <<= 1) {
        const int t = (tid >= off) ? sh[tid - off] : 0;
        __syncthreads();
        val += t;
        sh[tid] = val;
        __syncthreads();
    }
    cnts[i] = val - v;
    if (tid == 1023) bsums[blockIdx.x] = val;
}

__global__ __launch_bounds__(1024) void scanC_k(int* __restrict__ cnts,
                                                const int* __restrict__ bsums,
                                                int* __restrict__ offs) {
    __shared__ int bs[128];
    const int tid = threadIdx.x;
    if (tid < 128) bs[tid] = (tid < SCAN_NBLK) ? bsums[tid] : 0;
    __syncthreads();
    for (int off = 1; off < 128; off <<= 1) {
        int t = 0;
        if (tid < 128 && tid >= off) t = bs[tid - off];
        __syncthreads();
        if (tid < 128) bs[tid] += t;
        __syncthreads();
    }
    const int add = (blockIdx.x == 0) ? 0 : bs[blockIdx.x - 1];
    const int i = blockIdx.x * 1024 + tid;
    cnts[i] += add;
    if (i == 0) offs[M_TOT] = E_TOT;
}

__global__ __launch_bounds__(256) void binplace_k(const int* __restrict__ ei,
                                                  const int* __restrict__ cnts,
                                                  uint* __restrict__ binned) {
    __shared__ int cur[NBKT];
    const int chunk = blockIdx.x;
    const int hop = chunk >> 6, c = chunk & 63;
    for (int b = threadIdx.x; b < NBKT; b += 256)
        cur[b] = cnts[((hop * NBKT + b) << 6) | c];
    __syncthreads();
    const int* srcp = ei + (size_t)hop * 2 * N_EDGES + c * CHE;
    const int* dstp = srcp + N_EDGES;
    for (int i = threadIdx.x; i < CHE; i += 256) {
        const int s = srcp[i], d = dstp[i];
        const int slot = atomicAdd(&cur[d >> 6], 1);
        binned[slot] = ((uint)(d & 63) << 16) | (uint)s;
    }
}

__global__ __launch_bounds__(256) void cat_k(const uint* __restrict__ binned,
                                             const int* __restrict__ cnts,
                                             int* __restrict__ offs,
                                             ushort* __restrict__ srcs) {
    const int B = blockIdx.x;
    const int hop = B >> 9, bb = B & 511;
    const int dstbase = bb << 6;
    if (dstbase >= N_NODES) return;
    const int bB = cnts[B << 6];
    const int bE = (B == NBKT_TOT - 1) ? E_TOT : cnts[(B + 1) << 6];
    const int cnt = bE - bB;

    __shared__ uint ent[2048];
    __shared__ ushort stg[2048];
    __shared__ int hist[64], cur[64];

    for (int d = threadIdx.x; d < 64; d += 256) hist[d] = 0;
    __syncthreads();
    for (int i = threadIdx.x; i < cnt; i += 256) {
        const uint e = binned[bB + i];
        ent[i] = e;
        atomicAdd(&hist[e >> 16], 1);
    }
    __syncthreads();
    if (threadIdx.x < 64) {
        const int v = hist[threadIdx.x];
        int x = v;
        for (int off = 1; off < 64; off <<= 1) {
            const int t = __shfl_up(x, off, 64);
            if (threadIdx.x >= off) x += t;
        }
        cur[threadIdx.x] = x - v;
        const int gd = dstbase + threadIdx.x;
        if (gd < N_NODES) offs[hop * N_NODES + gd] = bB + x - v;
    }
    __syncthreads();
    for (int i = threadIdx.x; i < cnt; i += 256) {
        const uint e = ent[i];
        const int lp = atomicAdd(&cur[e >> 16], 1);
        stg[lp] = (ushort)(e & 0xffffu);
    }
    __syncthreads();
    for (int i = threadIdx.x; i < cnt; i += 256)
        srcs[bB + i] = stg[i];
}

// ---------------- GIN aggregation: COLUMN-SPLIT 2 passes ----------------
// Per (pass,hop) phase the gather working set is 3.84 MB -> per-XCD L2
// resident (phase-major doubled grid; ~2000 resident blocks << 7500/phase).
// 8 edge-streams x 8 lanes x uint4 (half-row 128B); 32 edges per granule,
// per-lane bytes-in-flight unchanged (4 x 16B). Clamp + dot2-mask as R15.
// zb written SWIZZLED for layerpar (swizzle stays within the pass's half).
__global__ __launch_bounds__(256) void agg_k(const ushort* __restrict__ xball,
                                             const int* __restrict__ offs,
                                             const ushort* __restrict__ srcs,
                                             const float* __restrict__ eps,
                                             ushort* __restrict__ zb) {
    const int bidx = blockIdx.x;
    const int pp = (bidx >= AGG_HALF) ? 1 : 0;           // column half
    const int gnode = (bidx - pp * AGG_HALF) * 4 + (threadIdx.x >> 6);
    const int hop = gnode / N_NODES;
    const int node = gnode - hop * N_NODES;
    const int lane = threadIdx.x & 63;
    const int eh = lane >> 3;            // edge stream 0..7
    const int cl = lane & 7;             // 16B chunk within the 128B half-row
    const float a = 1.0f + eps[hop];
    const char* xb = (const char*)(xball + (size_t)(hop + 1) * N_NODES * D);
    const uint coff = (uint)(pp * 128 + cl * 16);
    const uint MLO = 0x00003F80u;        // bf16 (1.0, 0)
    const uint MHI = 0x3F800000u;        // bf16 (0, 1.0)

    float acc[8];
#pragma unroll
    for (int q = 0; q < 8; ++q) acc[q] = 0.f;
    if (eh == 0) {                       // self term on stream 0
        const uint4 sv = *(const uint4*)(xb + (((uint)node << 8) + coff));
        const uint w[4] = {sv.x, sv.y, sv.z, sv.w};
#pragma unroll
        for (int q = 0; q < 4; ++q) {
            acc[2 * q]     = a * bf2f((ushort)(w[q] & 0xffff));
            acc[2 * q + 1] = a * bf2f((ushort)(w[q] >> 16));
        }
    }

    const int beg = offs[gnode], end = offs[gnode + 1];
    for (int i = beg; i < end; i += 32) {
        uint4 v[4];
        uint mlo[4], mhi[4];
#pragma unroll
        for (int u = 0; u < 4; ++u) {
            const int p = i + u * 8 + eh;
            const int pc = min(p, end - 1);          // valid: end > i >= beg
            const uint boff = ((uint)srcs[pc] << 8) + coff;
            v[u] = *(const uint4*)(xb + boff);
            const bool ok = p < end;
            mlo[u] = ok ? MLO : 0u;
            mhi[u] = ok ? MHI : 0u;
        }
#pragma unroll
        for (int u = 0; u < 4; ++u) {
            DOT2(acc[0], v[u].x, mlo[u]); DOT2(acc[1], v[u].x, mhi[u]);
            DOT2(acc[2], v[u].y, mlo[u]); DOT2(acc[3], v[u].y, mhi[u]);
            DOT2(acc[4], v[u].z, mlo[u]); DOT2(acc[5], v[u].z, mhi[u]);
            DOT2(acc[6], v[u].w, mlo[u]); DOT2(acc[7], v[u].w, mhi[u]);
        }
    }
#pragma unroll
    for (int q = 0; q < 8; ++q) {
        acc[q] += __shfl_xor(acc[q], 8);
        acc[q] += __shfl_xor(acc[q], 16);
        acc[q] += __shfl_xor(acc[q], 32);
    }
    if (eh == 0) {
        uint4 o;
        o.x = (uint)f2bf(acc[0]) | ((uint)f2bf(acc[1]) << 16);
        o.y = (uint)f2bf(acc[2]) | ((uint)f2bf(acc[3]) << 16);
        o.z = (uint)f2bf(acc[4]) | ((uint)f2bf(acc[5]) << 16);
        o.w = (uint)f2bf(acc[6]) | ((uint)f2bf(acc[7]) << 16);
        // swizzled store: chunk pp*8+cl of row gnode lands at chunk^(gnode&7)
        // (XOR affects only low 3 bits -> stays within this pass's half)
        ((uint4*)zb)[(size_t)gnode * 16 + ((pp * 8 + cl) ^ (gnode & 7))] = o;
    }
}

// ---------------- driver ----------------
extern "C" void kernel_launch(void* const* d_in, const int* in_sizes, int n_in,
                              void* d_out, int out_size, void* d_ws, size_t ws_size,
                              hipStream_t stream)
{
    const float* xs  = (const float*)d_in[0];
    const int*   ei  = (const int*)d_in[1];
    const float* lW1 = (const float*)d_in[2];
    const float* lb1 = (const float*)d_in[3];
    const float* lg  = (const float*)d_in[4];
    const float* lbt = (const float*)d_in[5];
    const float* lm  = (const float*)d_in[6];
    const float* lv  = (const float*)d_in[7];
    const float* lW2 = (const float*)d_in[8];
    const float* lb2 = (const float*)d_in[9];
    const float* eps = (const float*)d_in[10];
    const float* cW1 = (const float*)d_in[11];
    const float* cb1 = (const float*)d_in[12];
    const float* cg  = (const float*)d_in[13];
    const float* cbt = (const float*)d_in[14];
    const float* cm  = (const float*)d_in[15];
    const float* cv  = (const float*)d_in[16];
    const float* cW2 = (const float*)d_in[17];
    const float* cb2 = (const float*)d_in[18];
    float* out = (float*)d_out;

    char* ws = (char*)d_ws;
    ushort* xball = (ushort*)ws; ws += (size_t)4 * N_NODES * D * sizeof(ushort);
    ushort* zb    = (ushort*)ws; ws += (size_t)H * N_NODES * D * sizeof(ushort);
    ushort* parts = (ushort*)ws; ws += (size_t)4 * N_NODES * D * sizeof(ushort);
    ushort* Wt    = (ushort*)ws; ws += (size_t)8 * D * D * sizeof(ushort);
    float*  scof  = (float*)ws;  ws += (size_t)(4 * 256 + 128) * sizeof(float);
    int* cnts     = (int*)ws;    ws += (size_t)CELLS * sizeof(int);
    int* bsums    = (int*)ws;    ws += 128 * sizeof(int);
    int* offs     = (int*)ws;    ws += (size_t)(M_TOT + 64) * sizeof(int);
    uint* binned  = (uint*)ws;   ws += (size_t)E_TOT * sizeof(uint);
    ushort* srcs  = (ushort*)ws;

    // merged prep: bincount, Wt (swizzled), scof, slice0 (swizzled), slices1-3
    prep_k<<<PREP_FIX + S0_BLK + CONV_BLK, 256, 0, stream>>>(
        xs, ei, lW1, lW2, cW1, cW2, lb1, lg, lbt, lm, lv,
        cb1, cg, cbt, cm, cv, lb2, cb2, Wt, scof, xball, cnts);

    // CSR scans + placement
    scanA_k<<<SCAN_NBLK, 1024, 0, stream>>>(cnts, bsums);
    scanC_k<<<SCAN_NBLK, 1024, 0, stream>>>(cnts, bsums, offs);
    binplace_k<<<H * NCH, 256, 0, stream>>>(ei, cnts, binned);
    cat_k<<<NBKT_TOT, 256, 0, stream>>>(binned, cnts, offs, srcs);

    // aggregation (2 column passes x 3 hops, phase-major), MLP, reduce
    agg_k<<<2 * AGG_HALF, 256, 0, stream>>>(xball, offs, srcs, eps, zb);
    layerpar_k<<<TILES * 4, 256, 0, stream>>>(xball, zb, Wt, scof, parts);
    reduce_k<<<(N_NODES * D / 4) / 256, 256, 0, stream>>>(parts, scof, out);
}

// Round 17
// 127.118 us; speedup vs baseline: 1.1828x; 1.1828x over previous
//
#include <hip/hip_runtime.h>

#define N_NODES 30000
#define N_EDGES 480000
#define D 128
#define H 3
#define BN_EPS 1e-5f
#define M_TOT (H * N_NODES)
#define E_TOT (H * N_EDGES)

#define NCH 64                       // chunks per hop
#define CHE (N_EDGES / NCH)          // 7500 edges per chunk
#define NBKT 512                     // dst buckets per hop (dst>>6)
#define NBKT_TOT (H * NBKT)          // 1536
#define CELLS (NBKT_TOT * NCH)       // 98304 = 96 * 1024
#define SCAN_NBLK (CELLS / 1024)     // 96
#define CONV_N4 (3 * N_NODES * D / 4)        // slices 1..3 (unswizzled, for agg)
#define CONV_BLK ((CONV_N4 + 255) / 256)     // 11250
#define TILES ((N_NODES + 63) / 64)          // 469
#define S0_BLK (N_NODES * 16 / 256)          // 1875: slice-0 swizzled conv
#define PREP_FIX (H * NCH + 9)               // 201

typedef __attribute__((ext_vector_type(8))) short short8v;   // 8 x bf16
typedef __attribute__((ext_vector_type(4))) float f32x4;     // MFMA accumulator

__device__ __forceinline__ ushort f2bf(float f) {            // RNE f32 -> bf16
    uint u = __float_as_uint(f);
    u += 0x7fffu + ((u >> 16) & 1u);
    return (ushort)(u >> 16);
}
__device__ __forceinline__ float bf2f(ushort b) {
    return __uint_as_float(((uint)b) << 16);
}

// acc += bf16_pair(w) . bf16_pair(msk)   (one VOP3P instruction)
#define DOT2(accv, w, msk) \
    asm("v_dot2_f32_bf16 %0, %1, %2, %0" : "+v"(accv) : "v"(w), "v"(msk))

// async global -> LDS, 16B per lane (dest = uniform base + lane*16)
__device__ __forceinline__ void gload16(const void* g, void* l) {
    __builtin_amdgcn_global_load_lds(
        (const __attribute__((address_space(1))) void*)g,
        (__attribute__((address_space(3))) void*)l, 16, 0, 0);
}

// ---------------- merged prep ----------------
// blocks: [0,192) bincount | [192,200) Wt^T swizzled | 200 scof |
// [201,201+1875) xs slice0 -> bf16 swizzled | rest: slices 1..3 unswizzled
__global__ __launch_bounds__(256) void prep_k(
    const float* __restrict__ xs, const int* __restrict__ ei,
    const float* __restrict__ lW1, const float* __restrict__ lW2,
    const float* __restrict__ cW1, const float* __restrict__ cW2,
    const float* __restrict__ lb1, const float* __restrict__ lg,
    const float* __restrict__ lbt, const float* __restrict__ lm,
    const float* __restrict__ lv,
    const float* __restrict__ cb1, const float* __restrict__ cg,
    const float* __restrict__ cbt, const float* __restrict__ cm,
    const float* __restrict__ cv,
    const float* __restrict__ lb2, const float* __restrict__ cb2,
    ushort* __restrict__ Wt, float* __restrict__ scof,
    ushort* __restrict__ xball, int* __restrict__ cnts)
{
    const int bid = blockIdx.x;
    const int tid = threadIdx.x;
    if (bid < H * NCH) {                     // CSR pass 1: per-chunk histogram
        __shared__ int hc[NBKT];
        const int hop = bid >> 6, c = bid & 63;
        for (int i = tid; i < NBKT; i += 256) hc[i] = 0;
        __syncthreads();
        const int* dstp = ei + (size_t)hop * 2 * N_EDGES + N_EDGES + c * CHE;
        for (int i = tid; i < CHE; i += 256)
            atomicAdd(&hc[dstp[i] >> 6], 1);
        __syncthreads();
        for (int b = tid; b < NBKT; b += 256)
            cnts[((hop * NBKT + b) << 6) | c] = hc[b];
    } else if (bid < H * NCH + 8) {          // Wt[n][k^swz] = W[k][n] (bf16)
        const int mat = bid - H * NCH;
        const float* src;
        if (mat == 0) src = lW1;
        else if (mat == 1) src = lW2;
        else {
            const int k = (mat - 2) >> 1;
            src = ((mat & 1) == 0 ? cW1 : cW2) + (size_t)k * D * D;
        }
        ushort* dst = Wt + (size_t)mat * D * D;
        for (int idx = tid; idx < D * D; idx += 256) {
            const int n = idx >> 7, k = idx & 127;
            dst[n * 128 + (k ^ ((n & 7) << 3))] = f2bf(src[k * D + n]);
        }
    } else if (bid == H * NCH + 8) {         // BN scale/offset + total bias
        for (int t = tid; t < 512; t += 256) {
            const int L = t >> 7, c = t & 127;
            float g, v, b, m, bt;
            if (L == 0) { g = lg[c]; v = lv[c]; b = lb1[c]; m = lm[c]; bt = lbt[c]; }
            else {
                const int k = L - 1;
                g = cg[k * D + c]; v = cv[k * D + c]; b = cb1[k * D + c];
                m = cm[k * D + c]; bt = cbt[k * D + c];
            }
            const float s = g * rsqrtf(v + BN_EPS);
            scof[L * 256 + c] = s;
            scof[L * 256 + 128 + c] = (b - m) * s + bt;
        }
        if (tid < 128) {                     // btot = lb2 + sum_k cb2[k]
            float t = lb2[tid];
            for (int k = 0; k < H; ++k) t += cb2[k * D + tid];
            scof[1024 + tid] = t;
        }
    } else if (bid < PREP_FIX + S0_BLK) {    // slice 0: f32 -> bf16, swizzled
        const int i = (bid - PREP_FIX) * 256 + tid;   // 16B chunk id
        const int row = i >> 4, c = i & 15;
        const float* sp = xs + (size_t)row * D + c * 8;
        const float4 f0 = ((const float4*)sp)[0];
        const float4 f1 = ((const float4*)sp)[1];
        uint4 o;
        o.x = (uint)f2bf(f0.x) | ((uint)f2bf(f0.y) << 16);
        o.y = (uint)f2bf(f0.z) | ((uint)f2bf(f0.w) << 16);
        o.z = (uint)f2bf(f1.x) | ((uint)f2bf(f1.y) << 16);
        o.w = (uint)f2bf(f1.z) | ((uint)f2bf(f1.w) << 16);
        ((uint4*)xball)[(size_t)row * 16 + (c ^ (row & 7))] = o;
    } else {                                 // slices 1..3 unswizzled (agg)
        const int i = (bid - PREP_FIX - S0_BLK) * 256 + tid;
        if (i < CONV_N4) {
            const float4 v = ((const float4*)(xs + (size_t)N_NODES * D))[i];
            ushort4 o;
            o.x = f2bf(v.x); o.y = f2bf(v.y); o.z = f2bf(v.z); o.w = f2bf(v.w);
            ((ushort4*)(xball + (size_t)N_NODES * D))[i] = o;
        }
    }
}

// ---------------- Layer-parallel MLP: async stage, ONE barrier -------------
__global__ __launch_bounds__(256) void layerpar_k(
    const ushort* __restrict__ xball, const ushort* __restrict__ zb,
    const ushort* __restrict__ Wt, const float* __restrict__ scof,
    ushort* __restrict__ parts)
{
    __shared__ ushort Xs[64 * 128];      // 16 KB
    __shared__ ushort Ws1[128 * 128];    // 32 KB
    __shared__ ushort Ws2[128 * 128];    // 32 KB
    const int L = blockIdx.x & 3, tile = blockIdx.x >> 2;
    const int row0 = tile * 64;
    const int tid = threadIdx.x;
    const int wave = tid >> 6, lane = tid & 63;
    const int m16 = lane & 15, kq = lane >> 4;

    const ushort* W1t = Wt + (size_t)(2 * L) * D * D;
    const ushort* W2t = W1t + D * D;
    const ushort* Xsrc = (L == 0) ? xball : zb + (size_t)(L - 1) * N_NODES * D;
    const float* scL = scof + L * 256;

#pragma unroll
    for (int it = 0; it < 4; ++it) {
        const int r = wave * 16 + it * 4;
        gload16(Xsrc + (size_t)(row0 + r) * 128 + lane * 8, &Xs[r * 128]);
    }
#pragma unroll
    for (int it = 0; it < 8; ++it) {
        const int r = wave * 32 + it * 4;
        gload16(W1t + (size_t)r * 128 + lane * 8, &Ws1[r * 128]);
        gload16(W2t + (size_t)r * 128 + lane * 8, &Ws2[r * 128]);
    }
    __syncthreads();   // waits vmcnt(0): all three tiles resident

    const int sx = (m16 & 7) << 3;

    short8v a[4];
#pragma unroll
    for (int kk = 0; kk < 4; ++kk)
        a[kk] = *(const short8v*)(&Xs[(wave * 16 + m16) * 128 + ((kk * 32 + kq * 8) ^ sx)]);

    f32x4 acc[8];
#pragma unroll
    for (int t = 0; t < 8; ++t) acc[t] = (f32x4){0.f, 0.f, 0.f, 0.f};
#pragma unroll
    for (int kk = 0; kk < 4; ++kk) {
#pragma unroll
        for (int t = 0; t < 8; ++t) {
            const short8v b = *(const short8v*)(&Ws1[(t * 16 + m16) * 128 + ((kk * 32 + kq * 8) ^ sx)]);
            acc[t] = __builtin_amdgcn_mfma_f32_16x16x32_bf16(a[kk], b, acc[t], 0, 0, 0);
        }
    }

#pragma unroll
    for (int t = 0; t < 8; ++t) {
        const int n = t * 16 + m16;
        const float sc = scL[n], of = scL[128 + n];
#pragma unroll
        for (int r = 0; r < 4; ++r) {
            const int ml = wave * 16 + kq * 4 + r;
            Xs[ml * 128 + (n ^ (((kq * 4 + r) & 7) << 3))] =
                f2bf(fmaxf(acc[t][r] * sc + of, 0.f));
        }
    }

    short8v ah[4];
#pragma unroll
    for (int kk = 0; kk < 4; ++kk)
        ah[kk] = *(const short8v*)(&Xs[(wave * 16 + m16) * 128 + ((kk * 32 + kq * 8) ^ sx)]);
    f32x4 accO[8];
#pragma unroll
    for (int t = 0; t < 8; ++t) accO[t] = (f32x4){0.f, 0.f, 0.f, 0.f};
#pragma unroll
    for (int kk = 0; kk < 4; ++kk) {
#pragma unroll
        for (int t = 0; t < 8; ++t) {
            const short8v b = *(const short8v*)(&Ws2[(t * 16 + m16) * 128 + ((kk * 32 + kq * 8) ^ sx)]);
            accO[t] = __builtin_amdgcn_mfma_f32_16x16x32_bf16(ah[kk], b, accO[t], 0, 0, 0);
        }
    }

    ushort* pL = parts + (size_t)L * N_NODES * D;
#pragma unroll
    for (int t = 0; t < 8; ++t) {
        const int n = t * 16 + m16;
#pragma unroll
        for (int r = 0; r < 4; ++r) {
            const int gr = row0 + wave * 16 + kq * 4 + r;
            if (gr < N_NODES) pL[(size_t)gr * D + n] = f2bf(accO[t][r]);
        }
    }
}

// ---------------- reduce: out = sum_L parts[L] + btot (f32, fixed order) ---
__global__ __launch_bounds__(256) void reduce_k(const ushort* __restrict__ parts,
                                                const float* __restrict__ scof,
                                                float* __restrict__ out)
{
    const int i = blockIdx.x * 256 + threadIdx.x;    // uint2 granule = 4 cols
    const size_t LS = (size_t)N_NODES * D / 4;       // uint2 per layer
    const uint2* pp = (const uint2*)parts;
    const uint2 q0 = pp[i];
    const uint2 q1 = pp[i + LS];
    const uint2 q2 = pp[i + 2 * LS];
    const uint2 q3 = pp[i + 3 * LS];
    const float4 bb = ((const float4*)(scof + 1024))[i & 31];
    float4 s;
    s.x = ((bf2f((ushort)(q0.x & 0xffff)) + bf2f((ushort)(q1.x & 0xffff))) +
           (bf2f((ushort)(q2.x & 0xffff)) + bf2f((ushort)(q3.x & 0xffff)))) + bb.x;
    s.y = ((bf2f((ushort)(q0.x >> 16)) + bf2f((ushort)(q1.x >> 16))) +
           (bf2f((ushort)(q2.x >> 16)) + bf2f((ushort)(q3.x >> 16)))) + bb.y;
    s.z = ((bf2f((ushort)(q0.y & 0xffff)) + bf2f((ushort)(q1.y & 0xffff))) +
           (bf2f((ushort)(q2.y & 0xffff)) + bf2f((ushort)(q3.y & 0xffff)))) + bb.z;
    s.w = ((bf2f((ushort)(q0.y >> 16)) + bf2f((ushort)(q1.y >> 16))) +
           (bf2f((ushort)(q2.y >> 16)) + bf2f((ushort)(q3.y >> 16)))) + bb.w;
    ((float4*)out)[i] = s;
}

// ---------------- CSR scans ----------------
__global__ __launch_bounds__(1024) void scanA_k(int* __restrict__ cnts,
                                                int* __restrict__ bsums) {
    __shared__ int sh[1024];
    const int tid = threadIdx.x;
    const int i = blockIdx.x * 1024 + tid;
    const int v = cnts[i];
    sh[tid] = v;
    __syncthreads();
    int val = v;
    for (int off = 1; off < 1024; off <<= 1) {
        const int t = (tid >= off) ? sh[tid - off] : 0;
        __syncthreads();
        val += t;
        sh[tid] = val;
        __syncthreads();
    }
    cnts[i] = val - v;
    if (tid == 1023) bsums[blockIdx.x] = val;
}

__global__ __launch_bounds__(1024) void scanC_k(int* __restrict__ cnts,
                                                const int* __restrict__ bsums,
                                                int* __restrict__ offs) {
    __shared__ int bs[128];
    const int tid = threadIdx.x;
    if (tid < 128) bs[tid] = (tid < SCAN_NBLK) ? bsums[tid] : 0;
    __syncthreads();
    for (int off = 1; off < 128; off <<= 1) {
        int t = 0;
        if (tid < 128 && tid >= off) t = bs[tid - off];
        __syncthreads();
        if (tid < 128) bs[tid] += t;
        __syncthreads();
    }
    const int add = (blockIdx.x == 0) ? 0 : bs[blockIdx.x - 1];
    const int i = blockIdx.x * 1024 + tid;
    cnts[i] += add;
    if (i == 0) offs[M_TOT] = E_TOT;
}

// binplace: int2-vectorized edge loads (CHE = 7500 even)
__global__ __launch_bounds__(256) void binplace_k(const int* __restrict__ ei,
                                                  const int* __restrict__ cnts,
                                                  uint* __restrict__ binned) {
    __shared__ int cur[NBKT];
    const int chunk = blockIdx.x;
    const int hop = chunk >> 6, c = chunk & 63;
    for (int b = threadIdx.x; b < NBKT; b += 256)
        cur[b] = cnts[((hop * NBKT + b) << 6) | c];
    __syncthreads();
    const int* srcp = ei + (size_t)hop * 2 * N_EDGES + c * CHE;
    const int* dstp = srcp + N_EDGES;
    for (int i2 = threadIdx.x; i2 < CHE / 2; i2 += 256) {
        const int2 s2 = ((const int2*)srcp)[i2];
        const int2 d2 = ((const int2*)dstp)[i2];
        const int slot0 = atomicAdd(&cur[d2.x >> 6], 1);
        binned[slot0] = ((uint)(d2.x & 63) << 16) | (uint)s2.x;
        const int slot1 = atomicAdd(&cur[d2.y >> 6], 1);
        binned[slot1] = ((uint)(d2.y & 63) << 16) | (uint)s2.y;
    }
}

// cat: per-wave sub-histograms + per-wave cursors (4x less LDS-atomic
// contention; deterministic — wave assignment of entries is fixed)
__global__ __launch_bounds__(256) void cat_k(const uint* __restrict__ binned,
                                             const int* __restrict__ cnts,
                                             int* __restrict__ offs,
                                             ushort* __restrict__ srcs) {
    const int B = blockIdx.x;
    const int hop = B >> 9, bb = B & 511;
    const int dstbase = bb << 6;
    if (dstbase >= N_NODES) return;
    const int bB = cnts[B << 6];
    const int bE = (B == NBKT_TOT - 1) ? E_TOT : cnts[(B + 1) << 6];
    const int cnt = bE - bB;
    const int tid = threadIdx.x;
    const int wave = tid >> 6;

    __shared__ uint ent[2048];
    __shared__ ushort stg[2048];
    __shared__ int hist[4][64];
    __shared__ int cur[4][64];

    hist[tid >> 6][tid & 63] = 0;            // 256 = 4*64 exactly
    __syncthreads();
    for (int i = tid; i < cnt; i += 256) {
        const uint e = binned[bB + i];
        ent[i] = e;
        atomicAdd(&hist[wave][e >> 16], 1);
    }
    __syncthreads();
    if (tid < 64) {                          // wave 0: totals + scans
        const int h0 = hist[0][tid], h1 = hist[1][tid];
        const int h2 = hist[2][tid], h3 = hist[3][tid];
        const int tot = (h0 + h1) + (h2 + h3);
        int x = tot;
        for (int off = 1; off < 64; off <<= 1) {
            const int t = __shfl_up(x, off, 64);
            if (tid >= off) x += t;
        }
        const int b0 = x - tot;              // exclusive base for this dst
        cur[0][tid] = b0;
        cur[1][tid] = b0 + h0;
        cur[2][tid] = b0 + h0 + h1;
        cur[3][tid] = b0 + h0 + h1 + h2;
        const int gd = dstbase + tid;
        if (gd < N_NODES) offs[hop * N_NODES + gd] = bB + b0;
    }
    __syncthreads();
    for (int i = tid; i < cnt; i += 256) {
        const uint e = ent[i];
        const int lp = atomicAdd(&cur[wave][e >> 16], 1);
        stg[lp] = (ushort)(e & 0xffffu);
    }
    __syncthreads();
    for (int i = tid; i < cnt; i += 256)
        srcs[bB + i] = stg[i];
}

// ---------------- GIN aggregation: 16-edge granule, clamp + dot2-mask ------
// (R15 version verbatim — measured 49.6 us = FETCH / 2.86 TB/s, the achieved
// random-256B-gather ceiling; R7/R16 cache-residency splits both regressed)
__global__ __launch_bounds__(256) void agg_k(const ushort* __restrict__ xball,
                                             const int* __restrict__ offs,
                                             const ushort* __restrict__ srcs,
                                             const float* __restrict__ eps,
                                             ushort* __restrict__ zb) {
    const int gnode = blockIdx.x * 4 + (threadIdx.x >> 6);   // 0..89999
    const int hop = gnode / N_NODES;
    const int node = gnode - hop * N_NODES;
    const int lane = threadIdx.x & 63;
    const int eh = lane >> 4;            // edge stream 0..3
    const int cl = lane & 15;            // 16B chunk within the 256B row
    const float a = 1.0f + eps[hop];
    const char* xb = (const char*)(xball + (size_t)(hop + 1) * N_NODES * D);
    const uint coff = (uint)cl << 4;
    const uint MLO = 0x00003F80u;        // bf16 (1.0, 0)
    const uint MHI = 0x3F800000u;        // bf16 (0, 1.0)

    float acc[8];
#pragma unroll
    for (int q = 0; q < 8; ++q) acc[q] = 0.f;
    if (eh == 0) {                       // self term on stream 0
        const uint4 sv = *(const uint4*)(xb + (((uint)node << 8) + coff));
        const uint w[4] = {sv.x, sv.y, sv.z, sv.w};
#pragma unroll
        for (int q = 0; q < 4; ++q) {
            acc[2 * q]     = a * bf2f((ushort)(w[q] & 0xffff));
            acc[2 * q + 1] = a * bf2f((ushort)(w[q] >> 16));
        }
    }

    const int beg = offs[gnode], end = offs[gnode + 1];
    for (int i = beg; i < end; i += 16) {
        uint4 v[4];
        uint mlo[4], mhi[4];
#pragma unroll
        for (int u = 0; u < 4; ++u) {
            const int p = i + u * 4 + eh;
            const int pc = min(p, end - 1);          // valid: end > i >= beg
            const uint boff = ((uint)srcs[pc] << 8) + coff;
            v[u] = *(const uint4*)(xb + boff);
            const bool ok = p < end;
            mlo[u] = ok ? MLO : 0u;
            mhi[u] = ok ? MHI : 0u;
        }
#pragma unroll
        for (int u = 0; u < 4; ++u) {
            DOT2(acc[0], v[u].x, mlo[u]); DOT2(acc[1], v[u].x, mhi[u]);
            DOT2(acc[2], v[u].y, mlo[u]); DOT2(acc[3], v[u].y, mhi[u]);
            DOT2(acc[4], v[u].z, mlo[u]); DOT2(acc[5], v[u].z, mhi[u]);
            DOT2(acc[6], v[u].w, mlo[u]); DOT2(acc[7], v[u].w, mhi[u]);
        }
    }
#pragma unroll
    for (int q = 0; q < 8; ++q) {
        acc[q] += __shfl_xor(acc[q], 16);
        acc[q] += __shfl_xor(acc[q], 32);
    }
    if (eh == 0) {
        uint4 o;
        o.x = (uint)f2bf(acc[0]) | ((uint)f2bf(acc[1]) << 16);
        o.y = (uint)f2bf(acc[2]) | ((uint)f2bf(acc[3]) << 16);
        o.z = (uint)f2bf(acc[4]) | ((uint)f2bf(acc[5]) << 16);
        o.w = (uint)f2bf(acc[6]) | ((uint)f2bf(acc[7]) << 16);
        // swizzled store: chunk c of row gnode lands at c ^ (gnode&7)
        ((uint4*)zb)[(size_t)gnode * 16 + (cl ^ (gnode & 7))] = o;
    }
}

// ---------------- driver ----------------
extern "C" void kernel_launch(void* const* d_in, const int* in_sizes, int n_in,
                              void* d_out, int out_size, void* d_ws, size_t ws_size,
                              hipStream_t stream)
{
    const float* xs  = (const float*)d_in[0];
    const int*   ei  = (const int*)d_in[1];
    const float* lW1 = (const float*)d_in[2];
    const float* lb1 = (const float*)d_in[3];
    const float* lg  = (const float*)d_in[4];
    const float* lbt = (const float*)d_in[5];
    const float* lm  = (const float*)d_in[6];
    const float* lv  = (const float*)d_in[7];
    const float* lW2 = (const float*)d_in[8];
    const float* lb2 = (const float*)d_in[9];
    const float* eps = (const float*)d_in[10];
    const float* cW1 = (const float*)d_in[11];
    const float* cb1 = (const float*)d_in[12];
    const float* cg  = (const float*)d_in[13];
    const float* cbt = (const float*)d_in[14];
    const float* cm  = (const float*)d_in[15];
    const float* cv  = (const float*)d_in[16];
    const float* cW2 = (const float*)d_in[17];
    const float* cb2 = (const float*)d_in[18];
    float* out = (float*)d_out;

    char* ws = (char*)d_ws;
    ushort* xball = (ushort*)ws; ws += (size_t)4 * N_NODES * D * sizeof(ushort);
    ushort* zb    = (ushort*)ws; ws += (size_t)H * N_NODES * D * sizeof(ushort);
    ushort* parts = (ushort*)ws; ws += (size_t)4 * N_NODES * D * sizeof(ushort);
    ushort* Wt    = (ushort*)ws; ws += (size_t)8 * D * D * sizeof(ushort);
    float*  scof  = (float*)ws;  ws += (size_t)(4 * 256 + 128) * sizeof(float);
    int* cnts     = (int*)ws;    ws += (size_t)CELLS * sizeof(int);
    int* bsums    = (int*)ws;    ws += 128 * sizeof(int);
    int* offs     = (int*)ws;    ws += (size_t)(M_TOT + 64) * sizeof(int);
    uint* binned  = (uint*)ws;   ws += (size_t)E_TOT * sizeof(uint);
    ushort* srcs  = (ushort*)ws;

    // merged prep: bincount, Wt (swizzled), scof, slice0 (swizzled), slices1-3
    prep_k<<<PREP_FIX + S0_BLK + CONV_BLK, 256, 0, stream>>>(
        xs, ei, lW1, lW2, cW1, cW2, lb1, lg, lbt, lm, lv,
        cb1, cg, cbt, cm, cv, lb2, cb2, Wt, scof, xball, cnts);

    // CSR scans + placement
    scanA_k<<<SCAN_NBLK, 1024, 0, stream>>>(cnts, bsums);
    scanC_k<<<SCAN_NBLK, 1024, 0, stream>>>(cnts, bsums, offs);
    binplace_k<<<H * NCH, 256, 0, stream>>>(ei, cnts, binned);
    cat_k<<<NBKT_TOT, 256, 0, stream>>>(binned, cnts, offs, srcs);

    // aggregation, layer-parallel MLP (async-staged), reduce
    agg_k<<<M_TOT / 4, 256, 0, stream>>>(xball, offs, srcs, eps, zb);
    layerpar_k<<<TILES * 4, 256, 0, stream>>>(xball, zb, Wt, scof, parts);
    reduce_k<<<(N_NODES * D / 4) / 256, 256, 0, stream>>>(parts, scof, out);
}